// Round 11
// baseline (316.083 us; speedup 1.0000x reference)
//
#include <hip/hip_runtime.h>
#include <hip/hip_bf16.h>

// MHA, softmax over model-dim AFTER A@V => plain accumulation, no online softmax.
// Round 11: attn 64 q-rows/wave (256 q/block, grid 8x32 = 256 blocks = 1/CU,
// __launch_bounds__(256,1) -> up to 512 VGPR). Doubles MFMA per unit of
// LDS-read/bounce/barrier overhead: 192 MFMA (~3700 SIMD-cyc) per wave-tile vs
// same 32KB LDS + 1 bounce -> predicted MfmaUtil 43%->60-72%. DMA staging,
// frag layouts, 3-term bf16 split, bounce pattern all byte-identical to r10.
// proj/presplit byte-identical to round 10 (verified).

#define NB 4
#define NS 2048
#define ND 128
#define NH 8
#define EPB (NS * ND)        // 262144 elems per (b,h)
#define XFRAGS (512 * 4)     // x: 8192 rows /16 * 4 kc
#define WFRAGS (3 * 64 * 4)  // W: 3 tensors * (1024/16) * 4 kc
#define PS_ELEMS ((size_t)2 * XFRAGS * 512 + (size_t)2 * WFRAGS * 512)  // 2,883,584

typedef unsigned short u16;
typedef unsigned int u32;
typedef short bf16x8 __attribute__((ext_vector_type(8)));
typedef float f32x4 __attribute__((ext_vector_type(4)));

struct __align__(16) us8 { u16 u[8]; };

#define MFMA(a, b, c) __builtin_amdgcn_mfma_f32_16x16x32_bf16((a), (b), (c), 0, 0, 0)

__device__ __forceinline__ void splitf(float f, u16& hi, u16& lo) {
    u32 fb = __float_as_uint(f);
    u32 hb = fb + 0x7FFFu + ((fb >> 16) & 1u);      // RNE to bf16
    hi = (u16)(hb >> 16);
    float fh = __uint_as_float((hb >> 16) << 16);
    float fl = f - fh;                               // exact residual
    u32 lb = __float_as_uint(fl);
    u32 lr = lb + 0x7FFFu + ((lb >> 16) & 1u);
    lo = (u16)(lr >> 16);
}

// ---------------------------------------------------------------------------
// Pre-split: x -> A-frag-ordered XH/XL, W{q,k,v} -> B-frag-ordered WH/WL.
// ---------------------------------------------------------------------------
__global__ __launch_bounds__(256) void presplit_kernel(
    const float* __restrict__ xg, const float* __restrict__ Wqg,
    const float* __restrict__ Wkg, const float* __restrict__ Wvg,
    u16* __restrict__ ps)
{
    const int gid = blockIdx.x * 256 + threadIdx.x;
    const int total = (XFRAGS + WFRAGS) * 64;
    if (gid >= total) return;
    const int fi = gid >> 6, l = gid & 63;
    const float* src;
    u16 *H, *L;
    if (fi < XFRAGS) {
        const int m16 = fi >> 2, kc = fi & 3;
        src = xg + (size_t)(m16 * 16 + (l & 15)) * ND + kc * 32 + (l >> 4) * 8;
        H = ps + (size_t)fi * 512 + l * 8;
        L = H + (size_t)XFRAGS * 512;
    } else {
        const int wfi = fi - XFRAGS;
        const int e16g = wfi >> 2, kc = wfi & 3;
        const int t = e16g >> 6, e16 = e16g & 63;
        const float* Wt = (t == 0) ? Wqg : (t == 1) ? Wkg : Wvg;
        src = Wt + (size_t)(e16 * 16 + (l & 15)) * ND + kc * 32 + (l >> 4) * 8;
        H = ps + (size_t)2 * XFRAGS * 512 + (size_t)wfi * 512 + l * 8;
        L = H + (size_t)WFRAGS * 512;
    }
    float4 v0 = *(const float4*)src;
    float4 v1 = *(const float4*)(src + 4);
    float vv[8] = { v0.x, v0.y, v0.z, v0.w, v1.x, v1.y, v1.z, v1.w };
    us8 hh, ll;
    #pragma unroll
    for (int j = 0; j < 8; ++j) splitf(vv[j], hh.u[j], ll.u[j]);
    *(us8*)H = hh;
    *(us8*)L = ll;
}

// ---------------------------------------------------------------------------
// Projection: pure-bf16 3-term split MFMA GEMM from pre-split frags.
// Byte-identical to round 10 (verified).
// ---------------------------------------------------------------------------
__global__ __launch_bounds__(256) void proj_kernel(
    const u16* __restrict__ ps, u16* __restrict__ ws, int b0, int nbh)
{
    __shared__ u32 sE[8192];   // 32KB epilogue bounce

    const int which = blockIdx.z;
    const int tid = threadIdx.x;
    const int wv = tid >> 6;
    const int l  = tid & 63;
    const int c  = l & 15;
    const int g  = l >> 4;
    const int wr = wv & 1;
    const int wc = wv >> 1;
    const int bx = blockIdx.x;
    const int bgl = bx >> 5;
    const int slb = (bx & 31) * 64;
    const int h = blockIdx.y;
    const int m0 = (b0 + bgl) * NS + slb;

    const u16* XH = ps;
    const u16* XL = ps + (size_t)XFRAGS * 512;
    const u16* WH = ps + (size_t)2 * XFRAGS * 512;
    const u16* WL = WH + (size_t)WFRAGS * 512;

    const int m16b = (m0 >> 4) + wr * 2;
    bf16x8 ah[2][4], al[2][4];
    #pragma unroll
    for (int mi = 0; mi < 2; ++mi)
        #pragma unroll
        for (int kc = 0; kc < 4; ++kc) {
            size_t f = ((size_t)(m16b + mi) * 4 + kc) * 512 + l * 8;
            ah[mi][kc] = *(const bf16x8*)(XH + f);
            al[mi][kc] = *(const bf16x8*)(XL + f);
        }

    f32x4 acc[2][4];
    #pragma unroll
    for (int mi = 0; mi < 2; ++mi)
        #pragma unroll
        for (int ni = 0; ni < 4; ++ni) acc[mi][ni] = (f32x4){0.f, 0.f, 0.f, 0.f};

    const int e16b = which * 64 + h * 8 + wc * 4;
    #pragma unroll
    for (int kc = 0; kc < 4; ++kc) {
        bf16x8 bh[4], bl[4];
        #pragma unroll
        for (int ni = 0; ni < 4; ++ni) {
            size_t f = ((size_t)(e16b + ni) * 4 + kc) * 512 + l * 8;
            bh[ni] = *(const bf16x8*)(WH + f);
            bl[ni] = *(const bf16x8*)(WL + f);
        }
        #pragma unroll
        for (int mi = 0; mi < 2; ++mi)
            #pragma unroll
            for (int ni = 0; ni < 4; ++ni) {
                acc[mi][ni] = MFMA(ah[mi][kc], bh[ni], acc[mi][ni]);
                acc[mi][ni] = MFMA(ah[mi][kc], bl[ni], acc[mi][ni]);
                acc[mi][ni] = MFMA(al[mi][kc], bh[ni], acc[mi][ni]);
            }
    }

    #pragma unroll
    for (int mi = 0; mi < 2; ++mi)
        #pragma unroll
        for (int ni = 0; ni < 4; ++ni)
            #pragma unroll
            for (int r = 0; r < 4; ++r) {
                const int slL = wr * 32 + mi * 16 + 4 * g + r;
                const int d   = wc * 64 + ni * 16 + c;
                u16 ph, pl;
                splitf(acc[mi][ni][r], ph, pl);
                u32 off;
                if (which == 0)
                    off = (u32)(((slL >> 4) * 4 + (d >> 5)) * 512
                          + ((d >> 3) & 3) * 128 + (slL & 15) * 8 + (d & 7));
                else if (which == 1)
                    off = (u32)(((((slL >> 5) * 4 + (d >> 5)) * 2 + ((slL >> 4) & 1)) * 512)
                          + ((d >> 3) & 3) * 128 + (slL & 15) * 8 + (d & 7));
                else
                    off = (u32)(((slL >> 5) * 8 + (d >> 4)) * 512
                          + ((slL >> 3) & 3) * 128 + (d & 15) * 8 + (slL & 7));
                sE[off] = (u32)ph | ((u32)pl << 16);
            }
    __syncthreads();

    const size_t TS = (size_t)nbh * EPB;
    const size_t tb = (size_t)(bgl * NH + h) * EPB;
    u16* HB = ws + (size_t)(2 * which) * TS + tb + (size_t)slb * 128;
    u16* LB = HB + TS;
    #pragma unroll
    for (int c4 = 0; c4 < 4; ++c4) {
        const int idx = c4 * 2048 + tid * 8;
        us8 hh, ll;
        #pragma unroll
        for (int j = 0; j < 8; ++j) {
            u32 v = sE[idx + j];
            hh.u[j] = (u16)(v & 0xFFFFu);
            ll.u[j] = (u16)(v >> 16);
        }
        *(us8*)(HB + idx) = hh;
        *(us8*)(LB + idx) = ll;
    }
}

// ---------------------------------------------------------------------------
// Attention: 4 waves x 64 q = 256 q/block, grid 8 x nbh (1 block/CU).
// Per 32-t tile: QK^T 96 MFMAs, per-mi bounce, PV 96 MFMAs. DMA dbuf staging.
// ---------------------------------------------------------------------------
__global__ __launch_bounds__(256, 1) void attn_kernel(
    const u16* __restrict__ ws, float* __restrict__ outg, int b0, int nbh)
{
    __shared__ __align__(16) u16 sbuf[2][4][4096];   // [dbuf][KH,KL,VH,VL][32t x 128d]
    __shared__ u32 sP[4][32 * 17];                   // per-wave per-mi P bounce

    const int tid = threadIdx.x;
    const int Wv = tid >> 6;
    const int l  = tid & 63;
    const int c  = l & 15;
    const int g  = l >> 4;
    const int bhl = blockIdx.y;
    const size_t tb = (size_t)bhl * EPB;
    const size_t TS = (size_t)nbh * EPB;

    const u16* QH = ws;
    const u16* QL = ws + 1 * TS;
    const u16* KH = ws + 2 * TS;
    const u16* KL = ws + 3 * TS;
    const u16* VH = ws + 4 * TS;
    const u16* VL = ws + 5 * TS;

    const int qb = blockIdx.x * 256 + Wv * 64;

    // Q fragments hi/lo (loop-invariant, registers): 4 mi x 4 kc x hi/lo
    bf16x8 qh[4][4], ql[4][4];
    #pragma unroll
    for (int mi = 0; mi < 4; ++mi)
        #pragma unroll
        for (int kc = 0; kc < 4; ++kc) {
            size_t f = tb + ((size_t)(((qb + 16 * mi) >> 4) * 4 + kc) * 64 + l) * 8;
            qh[mi][kc] = *(const bf16x8*)(QH + f);
            ql[mi][kc] = *(const bf16x8*)(QL + f);
        }

    f32x4 z[4][8];
    #pragma unroll
    for (int mi = 0; mi < 4; ++mi)
        #pragma unroll
        for (int ni = 0; ni < 8; ++ni) z[mi][ni] = (f32x4){0.f, 0.f, 0.f, 0.f};

    const u16* srcs[4] = { KH, KL, VH, VL };
    auto stage = [&](int buf, int T) {
        #pragma unroll
        for (int t4 = 0; t4 < 4; ++t4)
            #pragma unroll
            for (int r = 0; r < 2; ++r)
                __builtin_amdgcn_global_load_lds(
                    (const __attribute__((address_space(1))) void*)
                        (srcs[t4] + tb + (size_t)T * 4096 + r * 2048 + tid * 8),
                    (__attribute__((address_space(3))) void*)
                        (&sbuf[buf][t4][r * 2048 + tid * 8]),
                    16, 0, 0);
    };

    u32* sPW = &sP[Wv][0];
    const float scale = 0.08838834764831845f;   // 1/sqrt(128)

    stage(0, 0);

    for (int T = 0; T < 64; ++T) {
        const int cur = T & 1;
        if (T < 63) {
            stage(cur ^ 1, T + 1);
            asm volatile("s_waitcnt vmcnt(8)" ::: "memory");   // cur tile landed
        } else {
            asm volatile("s_waitcnt vmcnt(0)" ::: "memory");
        }
        __builtin_amdgcn_s_barrier();
        asm volatile("" ::: "memory");

        const u16* bKH = &sbuf[cur][0][0];
        const u16* bKL = &sbuf[cur][1][0];
        const u16* bVH = &sbuf[cur][2][0];
        const u16* bVL = &sbuf[cur][3][0];

        // ---- QK^T: S = Qh*Kh + Qh*Kl + Ql*Kh (96 MFMAs) ----
        f32x4 s[4][2];
        #pragma unroll
        for (int mi = 0; mi < 4; ++mi)
            #pragma unroll
            for (int nt = 0; nt < 2; ++nt) s[mi][nt] = (f32x4){0.f, 0.f, 0.f, 0.f};
        __builtin_amdgcn_s_setprio(1);
        #pragma unroll
        for (int kc = 0; kc < 4; ++kc) {
            bf16x8 kh0 = *(const bf16x8*)(bKH + ((kc * 2 + 0) * 64 + l) * 8);
            bf16x8 kh1 = *(const bf16x8*)(bKH + ((kc * 2 + 1) * 64 + l) * 8);
            bf16x8 kl0 = *(const bf16x8*)(bKL + ((kc * 2 + 0) * 64 + l) * 8);
            bf16x8 kl1 = *(const bf16x8*)(bKL + ((kc * 2 + 1) * 64 + l) * 8);
            #pragma unroll
            for (int mi = 0; mi < 4; ++mi) {
                s[mi][0] = MFMA(qh[mi][kc], kh0, s[mi][0]);
                s[mi][0] = MFMA(qh[mi][kc], kl0, s[mi][0]);
                s[mi][0] = MFMA(ql[mi][kc], kh0, s[mi][0]);
                s[mi][1] = MFMA(qh[mi][kc], kh1, s[mi][1]);
                s[mi][1] = MFMA(qh[mi][kc], kl1, s[mi][1]);
                s[mi][1] = MFMA(ql[mi][kc], kh1, s[mi][1]);
            }
        }
        __builtin_amdgcn_s_setprio(0);

        // ---- per-mi P bounce: C-layout -> A-layout, bf16 hi/lo packed ----
        bf16x8 pa_h[4], pa_l[4];
        #pragma unroll
        for (int mi = 0; mi < 4; ++mi) {
            #pragma unroll
            for (int nt = 0; nt < 2; ++nt)
                #pragma unroll
                for (int r = 0; r < 4; ++r) {
                    float p = s[mi][nt][r] * scale;
                    u16 ph, pl; splitf(p, ph, pl);
                    sPW[(nt * 16 + c) * 17 + 4 * g + r] = (u32)ph | ((u32)pl << 16);
                }
            union { u16 uh[8]; bf16x8 v; } ph8;
            union { u16 ul[8]; bf16x8 v; } pl8;
            #pragma unroll
            for (int j = 0; j < 8; ++j) {
                u32 v = sPW[(8 * g + j) * 17 + c];
                ph8.uh[j] = (u16)(v & 0xFFFFu);
                pl8.ul[j] = (u16)(v >> 16);
            }
            pa_h[mi] = ph8.v;
            pa_l[mi] = pl8.v;
        }

        // ---- PV: Z += Ph*Vh + Ph*Vl + Pl*Vh (96 MFMAs) ----
        __builtin_amdgcn_s_setprio(1);
        #pragma unroll
        for (int ni = 0; ni < 8; ++ni) {
            bf16x8 vh = *(const bf16x8*)(bVH + (ni * 64 + l) * 8);
            bf16x8 vl = *(const bf16x8*)(bVL + (ni * 64 + l) * 8);
            #pragma unroll
            for (int mi = 0; mi < 4; ++mi) {
                z[mi][ni] = MFMA(pa_h[mi], vh, z[mi][ni]);
                z[mi][ni] = MFMA(pa_h[mi], vl, z[mi][ni]);
                z[mi][ni] = MFMA(pa_l[mi], vh, z[mi][ni]);
            }
        }
        __builtin_amdgcn_s_setprio(0);

        asm volatile("" ::: "memory");
        __builtin_amdgcn_s_barrier();   // all waves done with buf[cur] before restage
    }

    // ---- softmax over D=128 per q-row, fp32 store ----
    const size_t obase = (size_t)(b0 * NH + bhl) * EPB;
    #pragma unroll
    for (int mi = 0; mi < 4; ++mi)
        #pragma unroll
        for (int r = 0; r < 4; ++r) {
            float v[8];
            float m = -3.4e38f;
            #pragma unroll
            for (int ni = 0; ni < 8; ++ni) { v[ni] = z[mi][ni][r]; m = fmaxf(m, v[ni]); }
            #pragma unroll
            for (int off = 1; off < 16; off <<= 1) m = fmaxf(m, __shfl_xor(m, off, 64));
            float sum = 0.f;
            #pragma unroll
            for (int ni = 0; ni < 8; ++ni) { v[ni] = expf(v[ni] - m); sum += v[ni]; }
            #pragma unroll
            for (int off = 1; off < 16; off <<= 1) sum += __shfl_xor(sum, off, 64);
            const float inv = 1.f / sum;
            const int q = qb + 16 * mi + 4 * g + r;
            #pragma unroll
            for (int ni = 0; ni < 8; ++ni)
                outg[obase + (size_t)q * ND + ni * 16 + c] = v[ni] * inv;
        }
}

extern "C" void kernel_launch(void* const* d_in, const int* in_sizes, int n_in,
                              void* d_out, int out_size, void* d_ws, size_t ws_size,
                              hipStream_t stream)
{
    (void)out_size;
    int xi = 0;
    for (int i = 0; i < n_in && i < 4; ++i)
        if (in_sizes[i] == NB * NS * ND) { xi = i; break; }
    const float* x = (const float*)d_in[xi];
    const float* Wsp[3]; int w = 0;
    for (int i = 0; i < 4; ++i) if (i != xi) Wsp[w++] = (const float*)d_in[i];
    const float* Wq = Wsp[0];
    const float* Wk = Wsp[1];
    const float* Wv = Wsp[2];
    float* out = (float*)d_out;
    u16* ws = (u16*)d_ws;

    auto need_bytes = [](int nb) {
        return ((size_t)6 * nb * NH * EPB + PS_ELEMS) * 2;
    };
    int nb = (ws_size >= need_bytes(4)) ? 4 : (ws_size >= need_bytes(2)) ? 2 : 1;
    const int nbh = nb * NH;
    u16* psb = ws + (size_t)6 * nbh * EPB;

    {
        const int total = (XFRAGS + WFRAGS) * 64;
        presplit_kernel<<<dim3((total + 255) / 256), dim3(256), 0, stream>>>(
            x, Wq, Wk, Wv, psb);
    }

    for (int b0 = 0; b0 < NB; b0 += nb) {
        proj_kernel<<<dim3(nb * 32, 8, 3), dim3(256), 0, stream>>>(
            psb, ws, b0, nbh);
        attn_kernel<<<dim3(NS / 256, nbh), dim3(256), 0, stream>>>(
            ws, out, b0, nbh);
    }
}